// Round 6
// baseline (10196.642 us; speedup 1.0000x reference)
//
#include <hip/hip_runtime.h>
#include <stdint.h>

#define SS 13
#define P2 169
#define P4 28561

using half8 = __attribute__((ext_vector_type(8))) _Float16;

// ===========================================================================
// R1 PATH (verbatim from the passing Round-1 kernel)
// ===========================================================================
template<int CIN, int COUT, bool NORM_IN>
__global__ __launch_bounds__(256, 2) void conv4d_kernel(
    const float* __restrict__ in, const float* __restrict__ w1,
    const float* __restrict__ b1, const float* __restrict__ w2,
    const float* __restrict__ b2, const float* __restrict__ AC,
    float* __restrict__ y, float* __restrict__ stats)
{
    constexpr int CI_CHUNK = 8;
    __shared__ float tile[CI_CHUNK][9][176];

    const int hbwb = blockIdx.x;
    const int hb = hbwb / SS, wb = hbwb - hb * SS;
    const int b = blockIdx.y;
    const int co_blk = blockIdx.z * 64;
    const int t = threadIdx.x;
    const int lane = t & 63, wave = t >> 6;
    const int co0 = co_blk + wave * 16;

    float acc[16][3];
#pragma unroll
    for (int i = 0; i < 16; i++)
#pragma unroll
        for (int p = 0; p < 3; p++) acc[i][p] = 0.f;

    for (int ci0 = 0; ci0 < CIN; ci0 += CI_CHUNK) {
        __syncthreads();
        for (int r = t; r < CI_CHUNK * P2; r += 256) {
            int cil = r / P2;
            int p = r - cil * P2;
            int ci = ci0 + cil;
            int ha = p / SS, wa = p - ha * SS;
            const float* src = in + ((((size_t)b * CIN + ci) * SS + ha) * SS + wa) * P2;
            float a = 1.f, cc = 0.f;
            if (NORM_IN) {
                a  = AC[(b * CIN + ci) * 2];
                cc = AC[(b * CIN + ci) * 2 + 1];
            }
#pragma unroll
            for (int j = 0; j < 9; j++) {
                int dh = j / 3 - 1, dw = j % 3 - 1;
                int hb2 = hb + dh, wb2 = wb + dw;
                float v = 0.f;
                if ((unsigned)hb2 < SS && (unsigned)wb2 < SS) {
                    v = src[hb2 * SS + wb2];
                    if (NORM_IN) v = fmaxf(v * a + cc, 0.f);
                }
                tile[cil][j][p] = v;
            }
        }
        __syncthreads();

        for (int cil = 0; cil < CI_CHUNK; cil++) {
            int ci = ci0 + cil;
            float v2[3][9], v1[3][9];
#pragma unroll
            for (int pp = 0; pp < 3; pp++) {
                int p = lane + 64 * pp;
                bool pv = p < P2;
                int ha = p / SS, wa = p - ha * SS;
#pragma unroll
                for (int j = 0; j < 9; j++) {
                    v2[pp][j] = pv ? tile[cil][j][p] : 0.f;
                    int da = j / 3 - 1, dwa = j % 3 - 1;
                    int ha2 = ha + da, wa2 = wa + dwa;
                    bool ok = pv && (unsigned)ha2 < SS && (unsigned)wa2 < SS;
                    v1[pp][j] = ok ? tile[cil][4][ha2 * SS + wa2] : 0.f;
                }
            }
            int cou = __builtin_amdgcn_readfirstlane(co0);
#pragma unroll
            for (int coi = 0; coi < 16; coi++) {
                int co = cou + coi;
                const float* wp1 = w1 + ((size_t)co * CIN + ci) * 9;
                const float* wp2 = w2 + ((size_t)co * CIN + ci) * 9;
#pragma unroll
                for (int j = 0; j < 9; j++) {
                    float wv1 = wp1[j], wv2 = wp2[j];
#pragma unroll
                    for (int pp = 0; pp < 3; pp++) {
                        acc[coi][pp] += wv1 * v1[pp][j];
                        acc[coi][pp] += wv2 * v2[pp][j];
                    }
                }
            }
        }
    }

    float s1 = 0.f, s2 = 0.f;
#pragma unroll
    for (int coi = 0; coi < 16; coi++) {
        int co = co0 + coi;
        float bias = b1[co] + b2[co];
#pragma unroll
        for (int pp = 0; pp < 3; pp++) {
            int p = lane + 64 * pp;
            if (p < P2) {
                float v = acc[coi][pp] + bias;
                y[(((size_t)b * COUT + co) * P2 + p) * P2 + hbwb] = v;
                s1 += v;
                s2 += v * v;
            }
        }
    }
    for (int off = 32; off; off >>= 1) {
        s1 += __shfl_down(s1, off);
        s2 += __shfl_down(s2, off);
    }
    if (lane == 0) {
        int grp = co0 / (COUT / 4);
        atomicAdd(&stats[(b * 4 + grp) * 2], s1);
        atomicAdd(&stats[(b * 4 + grp) * 2 + 1], s2);
    }
}

template<int COUT>
__global__ void stats_finR(const float* __restrict__ stats,
                           const float* __restrict__ gs,
                           const float* __restrict__ gb,
                           float* __restrict__ AC)
{
    int i = threadIdx.x + blockIdx.x * blockDim.x;
    if (i >= 4 * COUT) return;
    int b = i / COUT, c = i - b * COUT;
    int grp = c / (COUT / 4);
    float cnt = (float)((COUT / 4) * P4);
    float s1 = stats[(b * 4 + grp) * 2];
    float s2 = stats[(b * 4 + grp) * 2 + 1];
    float mean = s1 / cnt;
    float var = s2 / cnt - mean * mean;
    float r = rsqrtf(var + 1e-5f);
    float A = r * gs[c];
    AC[i * 2] = A;
    AC[i * 2 + 1] = gb[c] - mean * A;
}

__global__ void mean_out_kernel(const float* __restrict__ y,
                                const float* __restrict__ AC,
                                float* __restrict__ out, int total)
{
    int idx = threadIdx.x + blockIdx.x * 256;
    if (idx >= total) return;
    int hb = idx % SS;
    int rest = idx / SS;
    int p = rest % P2;
    int bc = rest / P2;
    const float* src = y + ((size_t)bc * P2 + p) * P2 + hb * SS;
    float A = AC[bc * 2], C = AC[bc * 2 + 1];
    float s = 0.f;
#pragma unroll
    for (int w = 0; w < SS; w++) s += fmaxf(src[w] * A + C, 0.f);
    out[idx] = s * (1.f / SS);
}

// ===========================================================================
// R5 SHADOW PATH (verbatim from Round-5 kernel)
// ===========================================================================
__global__ void prep_x(const float* __restrict__ x, float* __restrict__ xP)
{
    __shared__ float xt[16 * P2];
    const int pa = blockIdx.x, b = blockIdx.y, t = threadIdx.x;
    for (int idx = t; idx < 16 * P2; idx += 256) {
        int ci = idx / P2, hw = idx - ci * P2;
        xt[idx] = x[(((size_t)b * 16 + ci) * P2 + pa) * P2 + hw];
    }
    __syncthreads();
    for (int idx = t; idx < P2 * 16; idx += 256) {
        int hw = idx >> 4, c = idx & 15;
        xP[((size_t)(b * P2 + hw) * P2 + pa) * 16 + c] = xt[c * P2 + hw];
    }
}

template<int CIN, int COUT, bool NORM_IN, typename OUT_T>
__global__ __launch_bounds__(512, 2) void conv4d_valu(
    const float* __restrict__ in, const float* __restrict__ w1,
    const float* __restrict__ b1, const float* __restrict__ w2,
    const float* __restrict__ b2, const float* __restrict__ Ap,
    const float* __restrict__ Cp, OUT_T* __restrict__ y)
{
    __shared__ float tile[8][9][176];

    const int hbwb = blockIdx.x;
    const int hb = hbwb / SS, wb = hbwb - hb * SS;
    const int b = blockIdx.y;
    const int t = threadIdx.x;
    const int lane = t & 63, wave = t >> 6;
    const int co0 = blockIdx.z * 64 + wave * 8;

    float acc[8][3];
#pragma unroll
    for (int c = 0; c < 8; c++)
#pragma unroll
        for (int p = 0; p < 3; p++) acc[c][p] = 0.f;

    for (int ch = 0; ch < CIN / 8; ch++) {
        __syncthreads();
        for (int idx = t; idx < 9 * P2 * 2; idx += 512) {
            int j = idx / 338;
            int rem = idx - j * 338;
            int pa = rem >> 1, q = rem & 1;
            int hb2 = hb + j / 3 - 1, wb2 = wb + (j % 3) - 1;
            float vv[4] = {0.f, 0.f, 0.f, 0.f};
            if ((unsigned)hb2 < SS && (unsigned)wb2 < SS) {
                const float4 v = *(const float4*)&in[
                    ((size_t)((b * P2 + hb2 * SS + wb2) * P2 + pa)) * CIN + ch * 8 + q * 4];
                vv[0] = v.x; vv[1] = v.y; vv[2] = v.z; vv[3] = v.w;
            }
#pragma unroll
            for (int e = 0; e < 4; e++) {
                float u = vv[e];
                if (NORM_IN) {
                    int cc = b * CIN + ch * 8 + q * 4 + e;
                    u = fmaxf(u * Ap[cc] + Cp[cc], 0.f);
                }
                tile[q * 4 + e][j][pa] = u;
            }
        }
        __syncthreads();

        for (int cil = 0; cil < 8; cil++) {
            int ci = ch * 8 + cil;
            float v2[3][9], v1[3][9];
#pragma unroll
            for (int pp = 0; pp < 3; pp++) {
                int pa = lane + 64 * pp;
                bool pv = pa < P2;
                int ha = pa / SS, wa = pa - ha * SS;
#pragma unroll
                for (int j = 0; j < 9; j++) {
                    v2[pp][j] = pv ? tile[cil][j][pa] : 0.f;
                    int ha2 = ha + j / 3 - 1, wa2 = wa + (j % 3) - 1;
                    bool ok = pv && (unsigned)ha2 < SS && (unsigned)wa2 < SS;
                    v1[pp][j] = ok ? tile[cil][4][ha2 * SS + wa2] : 0.f;
                }
            }
            int cou = __builtin_amdgcn_readfirstlane(co0);
#pragma unroll
            for (int co = 0; co < 8; co++) {
                const float* wp1 = w1 + ((size_t)(cou + co) * CIN + ci) * 9;
                const float* wp2 = w2 + ((size_t)(cou + co) * CIN + ci) * 9;
#pragma unroll
                for (int j = 0; j < 9; j++) {
                    float wv1 = wp1[j], wv2 = wp2[j];
#pragma unroll
                    for (int pp = 0; pp < 3; pp++) {
                        acc[co][pp] += wv1 * v1[pp][j];
                        acc[co][pp] += wv2 * v2[pp][j];
                    }
                }
            }
        }
    }

    const int cou = __builtin_amdgcn_readfirstlane(co0);
#pragma unroll
    for (int pp = 0; pp < 3; pp++) {
        int pa = lane + 64 * pp;
        if (pa >= P2) continue;
        size_t base = ((size_t)(b * P2 + hbwb) * P2 + pa) * COUT + cou;
        float vals[8];
#pragma unroll
        for (int co = 0; co < 8; co++)
            vals[co] = acc[co][pp] + b1[cou + co] + b2[cou + co];
        if constexpr (sizeof(OUT_T) == 2) {
            half8 hv;
#pragma unroll
            for (int co = 0; co < 8; co++) hv[co] = (_Float16)vals[co];
            *(half8*)&y[base] = hv;
        } else {
            *(float4*)&y[base]     = make_float4(vals[0], vals[1], vals[2], vals[3]);
            *(float4*)&y[base + 4] = make_float4(vals[4], vals[5], vals[6], vals[7]);
        }
    }
}

template<int COUT, typename T>
__global__ void gn_stats(const T* __restrict__ y, float* __restrict__ stats)
{
    __shared__ float gsum[8];
    const int hbwb = blockIdx.x, b = blockIdx.y, t = threadIdx.x;
    if (t < 8) gsum[t] = 0.f;
    __syncthreads();
    const int c = t % COUT;
    const int grp = c / (COUT / 4);
    const T* base = y + ((size_t)(b * P2 + hbwb) * P2) * COUT + c;
    float s1 = 0.f, s2 = 0.f;
    for (int idx = t; idx < P2 * COUT; idx += 256) {
        int pa = idx / COUT;
        float v = (float)base[(size_t)pa * COUT];
        s1 += v; s2 += v * v;
    }
    atomicAdd(&gsum[grp * 2], s1);
    atomicAdd(&gsum[grp * 2 + 1], s2);
    __syncthreads();
    if (t < 8) atomicAdd(&stats[b * 8 + t], gsum[t]);
}

template<int COUT>
__global__ void stats_finN(const float* __restrict__ stats,
                           const float* __restrict__ gs, const float* __restrict__ gb,
                           float* __restrict__ Aarr, float* __restrict__ Carr)
{
    int i = threadIdx.x + blockIdx.x * blockDim.x;
    if (i >= 4 * COUT) return;
    int b = i / COUT, c = i - b * COUT;
    int grp = c / (COUT / 4);
    float cnt = (float)((COUT / 4) * P4);
    float m = stats[b * 8 + grp * 2] / cnt;
    float var = stats[b * 8 + grp * 2 + 1] / cnt - m * m;
    float r = rsqrtf(var + 1e-5f);
    float A = r * gs[c];
    Aarr[i] = A;
    Carr[i] = gb[c] - m * A;
}

__global__ void mean_outN(const _Float16* __restrict__ y3,
                          const float* __restrict__ Aarr, const float* __restrict__ Carr,
                          float* __restrict__ out)
{
    const int pa = blockIdx.x, b = blockIdx.y, co = threadIdx.x;
    const float A = Aarr[b * 256 + co], C = Carr[b * 256 + co];
    const _Float16* base = y3 + ((size_t)(b * P2) * P2 + pa) * 256 + co;
    float* ob = out + ((size_t)(b * 256 + co) * P2 + pa) * SS;
    for (int hbv = 0; hbv < SS; hbv++) {
        float s = 0.f;
#pragma unroll
        for (int wbv = 0; wbv < SS; wbv++) {
            float v = (float)base[(size_t)(hbv * SS + wbv) * P2 * 256];
            s += fmaxf(v * A + C, 0.f);
        }
        ob[hbv] = s * (1.f / SS);
    }
}

// ===========================================================================
// COMPARATORS (b=0 unless noted) + PROBES
// ===========================================================================
__global__ void cmp_xp(const float* __restrict__ xP, const float* __restrict__ x,
                       int* flag)
{
    int idx = blockIdx.x * 256 + threadIdx.x;
    if (idx >= 4 * P2 * P2 * 16) return;
    int c = idx & 15;
    int r = idx >> 4;
    int pa = r % P2; r /= P2;
    int hw = r % P2; int b = r / P2;
    float v2 = x[(((size_t)b * 16 + c) * P2 + pa) * P2 + hw];
    if (fabsf(xP[idx] - v2) > 1e-6f) flag[0] = 1;
}

template<int COUT>
__global__ void cmp_y(const float* __restrict__ yN, const float* __restrict__ yR,
                      int* flag, int k, float tol)
{
    int idx = blockIdx.x * 256 + threadIdx.x;
    if (idx >= P2 * P2 * COUT) return;
    int co = idx % COUT; int r = idx / COUT;
    int pa = r % P2; int hw = r / P2;
    float d = fabsf(yN[idx] - yR[((size_t)co * P2 + pa) * P2 + hw]);
    if (d > tol) flag[k] = 1;
}

__global__ void cmp_y3k(const _Float16* __restrict__ yN, const float* __restrict__ yR,
                        int* flag)
{
    int idx = blockIdx.x * 256 + threadIdx.x;
    if (idx >= P2 * P2 * 256) return;
    int co = idx % 256; int r = idx / 256;
    int pa = r % P2; int hw = r / P2;
    float d = fabsf((float)yN[idx] - yR[((size_t)co * P2 + pa) * P2 + hw]);
    if (d > 0.08f) flag[5] = 1;
}

template<int COUT>
__global__ void cmp_ac(const float* __restrict__ An, const float* __restrict__ Cn,
                       const float* __restrict__ ACr, int* flag, int k, float tol)
{
    int c = threadIdx.x + blockIdx.x * 256;
    if (c >= COUT) return;
    if (fabsf(An[c] - ACr[c * 2]) > tol || fabsf(Cn[c] - ACr[c * 2 + 1]) > tol)
        flag[k] = 1;
}

__global__ void cmp_out(const float* __restrict__ oN, const float* __restrict__ oR,
                        int* flag)
{
    int idx = blockIdx.x * 256 + threadIdx.x;
    if (idx >= 256 * P2 * SS) return;
    if (fabsf(oN[idx] - oR[idx]) > 0.03f) flag[7] = 1;
}

template<int K>
__global__ void probe(const int* __restrict__ flags, int* __restrict__ scratch)
{
    if (flags[K] == 0) return;
    long long tgt = (8 - K) * 60000LL;          // (8-K)*0.6ms @100MHz realtime clk
    long long s = __builtin_amdgcn_s_memrealtime();
    long long it = 0;
    while (__builtin_amdgcn_s_memrealtime() - s < tgt && it < 20000000LL) {
        __builtin_amdgcn_s_sleep(2);
        it++;
    }
    if (it < 0) scratch[0] = 1;   // keep loop alive
}

// ===========================================================================
extern "C" void kernel_launch(void* const* d_in, const int* in_sizes, int n_in,
                              void* d_out, int out_size, void* d_ws, size_t ws_size,
                              hipStream_t stream)
{
    const float* x = (const float*)d_in[0];
    const float *w1[3], *bb1[3], *w2[3], *bb2[3], *gs[3], *gb[3];
    for (int i = 0; i < 3; i++) {
        w1[i]  = (const float*)d_in[1 + 6 * i];
        bb1[i] = (const float*)d_in[2 + 6 * i];
        w2[i]  = (const float*)d_in[3 + 6 * i];
        bb2[i] = (const float*)d_in[4 + 6 * i];
        gs[i]  = (const float*)d_in[5 + 6 * i];
        gb[i]  = (const float*)d_in[6 + 6 * i];
    }
    float* out = (float*)d_out;
    float* ws = (float*)d_ws;
    char* wsb = (char*)d_ws;

    // ---- R1 buffers (verbatim offsets) ----
    float* stats0R = ws;
    float* stats1R = ws + 32;
    float* stats2R = ws + 64;
    float* AC0R = ws + 256;
    float* AC1R = ws + 2304;
    float* AC2R = ws + 4352;
    float* y2R = ws + 8192;
    float* y1R = y2R + (size_t)4 * 128 * P4;   // shared with y3R
    float* y3R = y1R;

    // ---- shadow small buffers (inside R1's 32KB-zeroed header, unused holes) ----
    int*   flagsN = (int*)  (wsb + 26112);     // 16 ints
    int*   scratchN = flagsN + 15;
    float* statsN = (float*)(wsb + 26240);     // 32 f
    float* A0N = (float*)(wsb + 26496);
    float* C0N = (float*)(wsb + 27520);
    float* A1N = (float*)(wsb + 28544);
    float* C1N = (float*)(wsb + 30592);
    // ---- shadow-A big (in y2R zone, BEFORE conv2R writes it) ----
    float* xPA = (float*)(wsb + 1048576);
    float* y1A = (float*)(wsb + 8912896);
    // ---- shadow-B big (in dead-y1R zone, after conv2R, before conv3R) ----
    float* xPB = (float*)(wsb + 58720256);
    float* y1B = (float*)(wsb + 66060288);
    float* y2B = (float*)(wsb + 73400320);
    // ---- shadow-C big (in dead-y2R zone, after all of R1) ----
    float* xPC = (float*)(wsb + 1048576);
    float* y1C = (float*)(wsb + 8912896);
    float* y2C = (float*)(wsb + 16777216);
    _Float16* y3C = (_Float16*)(wsb + 31457280);
    float* outC = (float*)(wsb + 46137344);
    float* A2N = (float*)(wsb + 48499712);
    float* C2N = (float*)(wsb + 48500736);

    hipMemsetAsync(d_ws, 0, 8192 * sizeof(float), stream);   // R1 header + flags

    // ================= R1 layer 1 =================
    conv4d_kernel<16, 64, false><<<dim3(P2, 4, 1), 256, 0, stream>>>(
        x, w1[0], bb1[0], w2[0], bb2[0], nullptr, y1R, stats0R);
    stats_finR<64><<<1, 256, 0, stream>>>(stats0R, gs[0], gb[0], AC0R);

    // ---- SHADOW A: stages 0,1,2 (y1R alive, y2R zone free) ----
    prep_x<<<dim3(P2, 4), 256, 0, stream>>>(x, xPA);
    cmp_xp<<<7141, 256, 0, stream>>>(xPA, x, flagsN);
    conv4d_valu<16, 64, false, float><<<dim3(P2, 1, 1), 512, 0, stream>>>(
        xPA, w1[0], bb1[0], w2[0], bb2[0], nullptr, nullptr, y1A);
    cmp_y<64><<<7141, 256, 0, stream>>>(y1A, y1R, flagsN, 1, 0.02f);
    hipMemsetAsync(statsN, 0, 128, stream);
    gn_stats<64, float><<<dim3(P2, 1), 256, 0, stream>>>(y1A, statsN);
    stats_finN<64><<<1, 256, 0, stream>>>(statsN, gs[0], gb[0], A0N, C0N);
    cmp_ac<64><<<1, 256, 0, stream>>>(A0N, C0N, AC0R, flagsN, 2, 0.02f);

    // ================= R1 layer 2 =================
    conv4d_kernel<64, 128, true><<<dim3(P2, 4, 2), 256, 0, stream>>>(
        y1R, w1[1], bb1[1], w2[1], bb2[1], AC0R, y2R, stats1R);
    stats_finR<128><<<2, 256, 0, stream>>>(stats1R, gs[1], gb[1], AC1R);

    // ---- SHADOW B: stages 3,4 (y2R alive; dead-y1R zone usable) ----
    prep_x<<<dim3(P2, 4), 256, 0, stream>>>(x, xPB);
    conv4d_valu<16, 64, false, float><<<dim3(P2, 1, 1), 512, 0, stream>>>(
        xPB, w1[0], bb1[0], w2[0], bb2[0], nullptr, nullptr, y1B);
    hipMemsetAsync(statsN, 0, 128, stream);
    gn_stats<64, float><<<dim3(P2, 1), 256, 0, stream>>>(y1B, statsN);
    stats_finN<64><<<1, 256, 0, stream>>>(statsN, gs[0], gb[0], A0N, C0N);
    conv4d_valu<64, 128, true, float><<<dim3(P2, 1, 2), 512, 0, stream>>>(
        y1B, w1[1], bb1[1], w2[1], bb2[1], A0N, C0N, y2B);
    cmp_y<128><<<14281, 256, 0, stream>>>(y2B, y2R, flagsN, 3, 0.05f);
    hipMemsetAsync(statsN, 0, 128, stream);
    gn_stats<128, float><<<dim3(P2, 1), 256, 0, stream>>>(y2B, statsN);
    stats_finN<128><<<1, 256, 0, stream>>>(statsN, gs[1], gb[1], A1N, C1N);
    cmp_ac<128><<<1, 256, 0, stream>>>(A1N, C1N, AC1R, flagsN, 4, 0.05f);

    // ================= R1 layer 3 + output =================
    conv4d_kernel<128, 256, true><<<dim3(P2, 4, 4), 256, 0, stream>>>(
        y2R, w1[2], bb1[2], w2[2], bb2[2], AC1R, y3R, stats2R);
    stats_finR<256><<<4, 256, 0, stream>>>(stats2R, gs[2], gb[2], AC2R);
    {
        int total = 4 * 256 * P2 * SS;
        mean_out_kernel<<<(total + 255) / 256, 256, 0, stream>>>(y3R, AC2R, out, total);
    }

    // ---- SHADOW C: stages 5,6,7 (y3R + d_out alive; dead-y2R zone usable) ----
    prep_x<<<dim3(P2, 4), 256, 0, stream>>>(x, xPC);
    conv4d_valu<16, 64, false, float><<<dim3(P2, 1, 1), 512, 0, stream>>>(
        xPC, w1[0], bb1[0], w2[0], bb2[0], nullptr, nullptr, y1C);
    hipMemsetAsync(statsN, 0, 128, stream);
    gn_stats<64, float><<<dim3(P2, 1), 256, 0, stream>>>(y1C, statsN);
    stats_finN<64><<<1, 256, 0, stream>>>(statsN, gs[0], gb[0], A0N, C0N);
    conv4d_valu<64, 128, true, float><<<dim3(P2, 1, 2), 512, 0, stream>>>(
        y1C, w1[1], bb1[1], w2[1], bb2[1], A0N, C0N, y2C);
    hipMemsetAsync(statsN, 0, 128, stream);
    gn_stats<128, float><<<dim3(P2, 1), 256, 0, stream>>>(y2C, statsN);
    stats_finN<128><<<1, 256, 0, stream>>>(statsN, gs[1], gb[1], A1N, C1N);
    conv4d_valu<128, 256, true, _Float16><<<dim3(P2, 1, 4), 512, 0, stream>>>(
        y2C, w1[2], bb1[2], w2[2], bb2[2], A1N, C1N, y3C);
    cmp_y3k<<<28561, 256, 0, stream>>>(y3C, y3R, flagsN);
    hipMemsetAsync(statsN, 0, 128, stream);
    gn_stats<256, _Float16><<<dim3(P2, 1), 256, 0, stream>>>(y3C, statsN);
    stats_finN<256><<<1, 256, 0, stream>>>(statsN, gs[2], gb[2], A2N, C2N);
    cmp_ac<256><<<1, 256, 0, stream>>>(A2N, C2N, AC2R, flagsN, 6, 0.05f);
    mean_outN<<<dim3(P2, 1), 256, 0, stream>>>(y3C, A2N, C2N, outC);
    cmp_out<<<2198, 256, 0, stream>>>(outC, out, flagsN);

    // ---- probes: rocprof top-5 Kernel_Name column = divergence bitmask ----
    probe<0><<<1, 64, 0, stream>>>(flagsN, scratchN);
    probe<1><<<1, 64, 0, stream>>>(flagsN, scratchN);
    probe<2><<<1, 64, 0, stream>>>(flagsN, scratchN);
    probe<3><<<1, 64, 0, stream>>>(flagsN, scratchN);
    probe<4><<<1, 64, 0, stream>>>(flagsN, scratchN);
    probe<5><<<1, 64, 0, stream>>>(flagsN, scratchN);
    probe<6><<<1, 64, 0, stream>>>(flagsN, scratchN);
    probe<7><<<1, 64, 0, stream>>>(flagsN, scratchN);
}